// Round 7
// baseline (535.101 us; speedup 1.0000x reference)
//
#include <hip/hip_runtime.h>

#define NB 1536
#define NS 1536
#define TSTEPS 4
#define KC  4.4294469180704688f  /* sqrt(2*9.81) */
#define HKC 2.2147234590352344f  /* 0.5*sqrt(2*9.81) */
#define CHUNK 32
#define NCH (NS / CHUNK)

// ---------------- ws layout (bytes) ----------------
#define OFF_KH4 0ull                                    // float2[NB] layer4 spigot0 (full k)
#define OFF_H   (OFF_KH4 + (unsigned long long)NB * 8)  // float[5*NB]
#define OFF_FB0 (OFF_H + 5ull * NB * 4)                 // float[2][NS] layer0 flows/2
#define OFF_PART (OFF_FB0 + 2ull * NS * 4)              // float[3][2][24][NS] partial flow/2 sums

static __device__ __forceinline__ float asqrt(float x) { return __builtin_amdgcn_sqrtf(x); }

// serial chain step: sub -> max -> sqrt -> fma ; flow/2 forks off-chain
#define SST(HK, HY, DST)                    \
  {                                         \
    float e_ = fmaxf(R - (HY), 0.0f);       \
    float q_ = asqrt(e_);                   \
    R = fmaf(-(HK), q_, R);                 \
    DST = (HK)*q_;                          \
  }

// ---------------- layer0 serial scan from LDS (single lane) ----------------
static __device__ void scan0_lds(const float4* __restrict__ k0, float* __restrict__ fbrow,
                                 float* __restrict__ H0, float P) {
  float R = P;
  float4 c0 = k0[0], c1 = k0[1], c2 = k0[2], c3 = k0[3];
  float4 n0 = k0[4], n1 = k0[5], n2 = k0[6], n3 = k0[7];
#pragma unroll 1
  for (int g = 0; g < NS / 8; ++g) {
    int mi = (g + 2 < NS / 8) ? 4 * g + 8 : 0;  // group g+2 (wrap dummy)
    float4 m0 = k0[mi], m1 = k0[mi + 1], m2 = k0[mi + 2], m3 = k0[mi + 3];
    float f0, f1, f2, f3, f4, f5, f6, f7;
    SST(c0.x, c0.y, f0) SST(c0.z, c0.w, f1)
    SST(c1.x, c1.y, f2) SST(c1.z, c1.w, f3)
    SST(c2.x, c2.y, f4) SST(c2.z, c2.w, f5)
    SST(c3.x, c3.y, f6) SST(c3.z, c3.w, f7)
    ((float4*)fbrow)[2 * g]     = make_float4(f0, f1, f2, f3);
    ((float4*)fbrow)[2 * g + 1] = make_float4(f4, f5, f6, f7);
    c0 = n0; c1 = n1; c2 = n2; c3 = n3;
    n0 = m0; n1 = m1; n2 = m2; n3 = m3;
  }
  *H0 = 2.0f * R - P;
}

// cooperative fuse of layer0 bucket0 row into LDS (contiguous reads)
static __device__ void fuse_k0(const float* __restrict__ th, const float* __restrict__ hh,
                               const float* __restrict__ aa, float2* __restrict__ k0t,
                               int tid, int nthr) {
  for (int s = tid; s < NS; s += nthr)
    k0t[s] = make_float2(th[s] * aa[s] * HKC, hh[s]);
}

// ---------------- prep: kh4 + H init + out zero + embedded layer0 scan t=0 ----------------
__global__ __launch_bounds__(256) void prep_k(const float* __restrict__ th,
                                              const float* __restrict__ hh,
                                              const float* __restrict__ aa,
                                              const float* __restrict__ Hinit,
                                              const float* __restrict__ precip,
                                              float2* __restrict__ kh4,
                                              float* __restrict__ H,
                                              float* __restrict__ fb0,
                                              float* __restrict__ out) {
  __shared__ float4 k0t4[NS / 2];
  if (blockIdx.x == 30) {  // layer0 scan, t=0
    fuse_k0(th, hh, aa, (float2*)k0t4, threadIdx.x, 256);
    __syncthreads();
    if (threadIdx.x) return;
    scan0_lds(k0t4, fb0 /*par0*/, H, Hinit[0] + precip[0] * 0.2f);
    return;
  }
  int i = blockIdx.x * 256 + threadIdx.x;
  if (i < NS) {
    size_t i4 = ((size_t)4 * NB + i) * NS;  // theta[4][i][0]
    kh4[i] = make_float2(th[i4] * aa[i4] * KC, hh[i4]);
  }
  if (i < 5 * NB && i != 0) H[i] = Hinit[i];  // H[0] written by scan0 block
  if (i < TSTEPS) out[i] = 0.0f;
}

// ---------------- stage kernel, one per anti-diagonal d = t + l ----------------
// blocks 0..23: l=1 (t=D-1) | 24..47: l=2 (t=D-2) | 48..71: l=3 (t=D-3)
// blocks 72..95: l=4 (t=D-4) | block 96: l=0 (t=D)
// 128 threads: wave0 = serial scan chain; wave1 = param stream/fuse/transpose + reduce.
template <int D>
__global__ __launch_bounds__(128) void stage_k(
    const float* __restrict__ th, const float* __restrict__ hh,
    const float* __restrict__ aa, const float2* __restrict__ kh4,
    float* __restrict__ H, float* __restrict__ fb0, float* __restrict__ part,
    const float* __restrict__ precip, float* __restrict__ out) {
  __shared__ float2 ptile[2][CHUNK][66];   // [buf][s_local][bucket(+pad)]
  __shared__ float red[2][CHUNK][64];      // [buf][s_local][lane]
  __shared__ float4 k0t4[NS / 2];          // layer0 path only
  int blk = blockIdx.x;
  int tid = threadIdx.x;
  int lane = tid & 63, wv = tid >> 6;

  if (blk == 96) {  // -------- layer0, t=D --------
    constexpr int t = D;
    if (t >= TSTEPS) return;
    fuse_k0(th, hh, aa, (float2*)k0t4, tid, 128);
    __syncthreads();
    if (tid) return;
    scan0_lds(k0t4, fb0 + (size_t)(t & 1) * NS, H, H[0] + precip[t] * 0.2f);
    return;
  }
  int track = blk / 24, b = blk % 24;
  const int l = track + 1;
  const int t = D - l;
  if (t < 0 || t >= TSTEPS) return;
  const int par = t & 1;
  float ppl = precip[t] * 0.2f;
  int j = b * 64 + lane;

  if (l == 4) {  // -------- layer4: colsum + single spigot + outflow --------
    if (wv) return;
    const float* pr = part + ((size_t)(4 + par) * 24) * NS + j;
    float s_ = 0.f;
#pragma unroll
    for (int i = 0; i < 24; ++i) s_ += pr[(size_t)i * NS];
    float P = H[4 * NB + j] + 2.0f * s_ + ppl * (1.0f / NB);
    float2 kh = kh4[j];
    float e = fmaxf(P - kh.y, 0.0f);
    float fl = kh.x * asqrt(e);
    H[4 * NB + j] = P - fl;
    for (int o = 32; o; o >>= 1) fl += __shfl_xor(fl, o);
    if (lane == 0) atomicAdd(out + t, fl);
    return;
  }

  // -------- layers 1..3: producer/consumer 2-wave scan --------
  size_t pbase = (size_t)l * NB * NS + (size_t)(b * 64) * NS;  // raw [b][s] base
  float* part_row = part + ((size_t)((l - 1) * 2 + par) * 24 + b) * NS;

  if (wv == 0) {
    // ---- scanner wave ----
    float inf;
    if (l == 1) {
      inf = 2.0f * fb0[(size_t)par * NS + j];
    } else {
      const float* pr = part + ((size_t)((l - 2) * 2 + par) * 24) * NS + j;
      float s_ = 0.f;
#pragma unroll
      for (int i = 0; i < 24; ++i) s_ += pr[(size_t)i * NS];
      inf = 2.0f * s_;
    }
    float P = H[(size_t)l * NB + j] + inf + ppl * (1.0f / NB);
    float R = P;
#define LD8(Q0,Q1,Q2,Q3,Q4,Q5,Q6,Q7, BUF, G)            \
    { const float2* pt_ = &ptile[BUF][(G) * 8][0];      \
      Q0 = pt_[0 * 66 + lane]; Q1 = pt_[1 * 66 + lane]; \
      Q2 = pt_[2 * 66 + lane]; Q3 = pt_[3 * 66 + lane]; \
      Q4 = pt_[4 * 66 + lane]; Q5 = pt_[5 * 66 + lane]; \
      Q6 = pt_[6 * 66 + lane]; Q7 = pt_[7 * 66 + lane]; }
#define CN8(Q0,Q1,Q2,Q3,Q4,Q5,Q6,Q7, BUF, G)                       \
    { float* rr_ = &red[BUF][(G) * 8][0];                          \
      SST(Q0.x, Q0.y, rr_[0 * 64 + lane])                          \
      SST(Q1.x, Q1.y, rr_[1 * 64 + lane])                          \
      SST(Q2.x, Q2.y, rr_[2 * 64 + lane])                          \
      SST(Q3.x, Q3.y, rr_[3 * 64 + lane])                          \
      SST(Q4.x, Q4.y, rr_[4 * 64 + lane])                          \
      SST(Q5.x, Q5.y, rr_[5 * 64 + lane])                          \
      SST(Q6.x, Q6.y, rr_[6 * 64 + lane])                          \
      SST(Q7.x, Q7.y, rr_[7 * 64 + lane]) }
#pragma unroll 1
    for (int c = 0; c < NCH; ++c) {
      __syncthreads();  // buf[c&1] filled during chunk c-1
      int bf = c & 1;
      float2 X0,X1,X2,X3,X4,X5,X6,X7, Y0,Y1,Y2,Y3,Y4,Y5,Y6,Y7;
      LD8(X0,X1,X2,X3,X4,X5,X6,X7, bf, 0)
      LD8(Y0,Y1,Y2,Y3,Y4,Y5,Y6,Y7, bf, 1)
      CN8(X0,X1,X2,X3,X4,X5,X6,X7, bf, 0)
      LD8(X0,X1,X2,X3,X4,X5,X6,X7, bf, 2)
      CN8(Y0,Y1,Y2,Y3,Y4,Y5,Y6,Y7, bf, 1)
      LD8(Y0,Y1,Y2,Y3,Y4,Y5,Y6,Y7, bf, 3)
      CN8(X0,X1,X2,X3,X4,X5,X6,X7, bf, 2)
      CN8(Y0,Y1,Y2,Y3,Y4,Y5,Y6,Y7, bf, 3)
    }
    __syncthreads();  // final red visible to wave1
    H[(size_t)l * NB + j] = 2.0f * R - P;
  } else {
    // ---- helper wave: fill chunk 0, then per chunk fill next + reduce prev ----
    int fr = lane >> 3, fs4 = lane & 7;  // row group, float4-in-s index
    // fill(buf, chunk cc):
#define FILL(BUF, CC)                                                        \
    { int s0_ = (CC) * CHUNK;                                                \
      _Pragma("unroll")                                                      \
      for (int k = 0; k < 8; ++k) {                                          \
        int r_ = fr + 8 * k;                                                 \
        size_t gi_ = pbase + (size_t)r_ * NS + s0_ + fs4 * 4;                \
        float4 t4_ = *(const float4*)(th + gi_);                             \
        float4 a4_ = *(const float4*)(aa + gi_);                             \
        float4 h4_ = *(const float4*)(hh + gi_);                             \
        float2* pt_ = &ptile[BUF][fs4 * 4][r_];                              \
        pt_[0 * 66] = make_float2(t4_.x * a4_.x * HKC, h4_.x);               \
        pt_[1 * 66] = make_float2(t4_.y * a4_.y * HKC, h4_.y);               \
        pt_[2 * 66] = make_float2(t4_.z * a4_.z * HKC, h4_.z);               \
        pt_[3 * 66] = make_float2(t4_.w * a4_.w * HKC, h4_.w);               \
      } }
    FILL(0, 0)
    int rs = lane & 31, rh = lane >> 5;
#pragma unroll 1
    for (int c = 0; c < NCH; ++c) {
      __syncthreads();
      if (c + 1 < NCH) FILL((c + 1) & 1, c + 1)
      if (c >= 1) {
        const float* rr = &red[(c - 1) & 1][rs][0];
        float acc = 0.f;
#pragma unroll
        for (int i = 0; i < 32; ++i) acc += rr[((i + lane) & 31) + rh * 32];
        acc += __shfl_xor(acc, 32);
        if (rh == 0) part_row[(c - 1) * CHUNK + rs] = acc;
      }
    }
    __syncthreads();
    {  // reduce last chunk
      const float* rr = &red[(NCH - 1) & 1][rs][0];
      float acc = 0.f;
#pragma unroll
      for (int i = 0; i < 32; ++i) acc += rr[((i + lane) & 31) + rh * 32];
      acc += __shfl_xor(acc, 32);
      if (rh == 0) part_row[(NCH - 1) * CHUNK + rs] = acc;
    }
  }
}

extern "C" void kernel_launch(void* const* d_in, const int* in_sizes, int n_in,
                              void* d_out, int out_size, void* d_ws,
                              size_t ws_size, hipStream_t stream) {
  const float* theta = (const float*)d_in[0];
  const float* sp_h = (const float*)d_in[1];
  const float* sp_a = (const float*)d_in[2];
  const float* Hinit = (const float*)d_in[3];
  const float* precip = (const float*)d_in[4];
  float* out = (float*)d_out;

  char* ws = (char*)d_ws;
  float2* kh4 = (float2*)(ws + OFF_KH4);
  float* H = (float*)(ws + OFF_H);
  float* fb0 = (float*)(ws + OFF_FB0);
  float* part = (float*)(ws + OFF_PART);

  hipLaunchKernelGGL(prep_k, dim3(31), dim3(256), 0, stream, theta, sp_h, sp_a,
                     Hinit, precip, kh4, H, fb0, out);
#define LAUNCH_STAGE(DD)                                                       \
  hipLaunchKernelGGL(HIP_KERNEL_NAME(stage_k<DD>), dim3(97), dim3(128), 0,     \
                     stream, theta, sp_h, sp_a, kh4, H, fb0, part, precip, out)
  LAUNCH_STAGE(1);
  LAUNCH_STAGE(2);
  LAUNCH_STAGE(3);
  LAUNCH_STAGE(4);
  LAUNCH_STAGE(5);
  LAUNCH_STAGE(6);
  LAUNCH_STAGE(7);
}